// Round 5
// baseline (978.607 us; speedup 1.0000x reference)
//
#include <hip/hip_runtime.h>
#include <hip/hip_bf16.h>
#include <cstdint>
#include <math.h>

#define TOKENS 4096
#define DMODEL 4096
#define DFF    16384

typedef __attribute__((ext_vector_type(4))) int i32x4;
typedef __attribute__((address_space(1))) unsigned int glb_u32;
typedef __attribute__((address_space(3))) unsigned int lds_u32;

// ---------------- pack: int32 -> int8 (values already in [-127,127]) ----------------
__global__ void pack_i8_kernel(const int* __restrict__ src, unsigned* __restrict__ dst, long n4) {
    long i = (long)blockIdx.x * blockDim.x + threadIdx.x;
    const long stride = (long)gridDim.x * blockDim.x;
    for (; i < n4; i += stride) {
        const int4 v = ((const int4*)src)[i];
        unsigned p = (unsigned(v.x) & 255u) | ((unsigned(v.y) & 255u) << 8) |
                     ((unsigned(v.z) & 255u) << 16) | ((unsigned(v.w) & 255u) << 24);
        dst[i] = p;
    }
}

__global__ void zero_u32_kernel(unsigned* __restrict__ p, int n) {
    int i = blockIdx.x * blockDim.x + threadIdx.x;
    if (i < n) p[i] = 0u;
}

// ---------------- int8 GEMM, C[row][col] = sum_k A[row][k]*B[col][k] ----------------
// 256x256 tile, BK=64, 8 waves (2M x 4N), wave tile 128x64 via 8x4 frags of
// 16x16x64 i8 MFMA. 4 LDS buffers (quad-buffer), staging 3 K-tiles ahead,
// vmcnt(8) once per K-tile (in-flight never < 8KB/wave -> latency-tolerant).
// 2 phases per K-tile t (buf = t&3):
//   P0: ds_read A m0-3 + B n0-3 (8 b128); stage A units (t+3);
//       bar; lgkm(0); 16 MFMA (m0-3); bar
//   P1: ds_read A m4-7 (4 b128); stage B units (t+3);
//       bar; lgkm(0); 16 MFMA (m4-7); vmcnt(8); bar
// vmcnt audit: at end-tile t, outstanding <= {t+1(4), t+2(4), t+3(4)};
// vmcnt(8) completes all of tile t+1 before K-tile t+1 reads its buf.
// Buf safety: stage into buf (t+3)&3 whose last reader (tile t-1) drained
// lgkm before its final barrier one K-tile ago. Tail restages tile nt-1
// (same bytes -> benign). LDS swizzle for 64B rows: chunk ^= (row>>1)&3
// -> frag ds_read_b128 exactly 2 lanes/bank (free); staging dest linear,
// source pre-swizzled g16 = ((lane&3)^((lane>>3)&3))*16 (lane-constant).
// XCD 2D chunking: 8 XCDs as 2x4 over tile grid; each XCD's 32 resident
// blocks form an 8-row x 4-col chunk (fresh bytes/XCD/K-tile 576->384KB).
template <int EPI>
__global__ __launch_bounds__(512)
void gemm_i8_kernel(const int8_t* __restrict__ A,
                    const int8_t* __restrict__ B,
                    const int Nout, const int K,
                    const float* __restrict__ scaleA,   // EPI1: in_scale[row]
                    const float* __restrict__ scaleB,   // w1_scale / w2_scale [col]
                    const float* __restrict__ bias,     // b1 / b2 [col]
                    unsigned* __restrict__ rowmax,      // EPI1: atomic out; EPI2: in
                    __hip_bfloat16* __restrict__ aout,  // EPI1: activations out
                    float* __restrict__ out)            // EPI2: final out
{
    __shared__ int8_t As[4][256 * 64];
    __shared__ int8_t Bs[4][256 * 64];

    const int tid  = threadIdx.x;
    const int lane = tid & 63;
    const int w    = tid >> 6;          // 0..7
    const int wm   = w >> 2;            // 0..1  (M half: 128 rows)
    const int wn   = w & 3;             // 0..3  (N quarter: 64 cols)
    const int l15  = lane & 15, l4 = lane >> 4;

    // ---- XCD-aware 2D chunk mapping (bijective; gy=16, gx%4==0 here) ----
    const int gx = gridDim.x, gy = gridDim.y;
    const int wg  = blockIdx.y * gx + blockIdx.x;
    const int xcd = wg & 7;             // hw round-robin heuristic
    const int idx = wg >> 3;
    const int xr = xcd >> 2, xc = xcd & 3;          // XCDs as 2 x 4
    const int strip = idx >> 5;                      // 4-col strips of 32 tiles
    const int row_t = xr * (gy >> 1) + ((idx & 31) >> 2);
    const int col_t = xc * (gx >> 2) + strip * 4 + (idx & 3);
    const int row0 = row_t * 256;
    const int col0 = col_t * 256;

    const int nt = K >> 6;

    // staging: pre-swizzled lane-constant source chunk for 64B rows
    const int g16 = ((lane & 3) ^ ((lane >> 3) & 3)) << 4;

    // frag ds_read addressing: row r, chunk c = l4 ^ ((r>>1)&3); (r>>1)&3 == (l15>>1)&3
    const int rbA = ((wm << 7) + l15) << 6;          // byte base; + m*1024
    const int rbB = ((wn << 6) + l15) << 6;          // byte base; + n*1024
    const int c0  = (l4 ^ ((l15 >> 1) & 3)) << 4;

    i32x4 fA[4], fB[4];
    i32x4 acc[8][4] = {};

    // one 8KB unit (128 rows x 64B) of operand P staged into LDS buf
#define STAGE_UNIT(P, p0q, LDSARR, bufi, t, u)                                        \
    {                                                                                 \
        const int8_t* src_ = (P) + (size_t)((p0q) + (u) * 128 + (w << 4) +            \
                             (lane >> 2)) * K + ((t) << 6) + g16;                     \
        int8_t* dst_ = &LDSARR[bufi][(u) * 8192 + (w << 10)];                         \
        __builtin_amdgcn_global_load_lds((glb_u32*)src_, (lds_u32*)dst_, 16, 0, 0);   \
    }

#define MFMA_Q(MB)                                                                    \
    {                                                                                 \
        __builtin_amdgcn_s_setprio(1);                                                \
        _Pragma("unroll")                                                             \
        for (int m_ = 0; m_ < 4; ++m_)                                                \
            _Pragma("unroll")                                                         \
            for (int n_ = 0; n_ < 4; ++n_)                                            \
                acc[(MB) + m_][n_] = __builtin_amdgcn_mfma_i32_16x16x64_i8(           \
                    fA[m_], fB[n_], acc[(MB) + m_][n_], 0, 0, 0);                     \
        __builtin_amdgcn_s_setprio(0);                                                \
    }

    // prologue: stage tiles 0,1,2 into bufs 0,1,2 (12 loads/wave)
#pragma unroll
    for (int tt = 0; tt < 3; ++tt) {
        STAGE_UNIT(A, row0, As, tt, tt, 0);
        STAGE_UNIT(A, row0, As, tt, tt, 1);
        STAGE_UNIT(B, col0, Bs, tt, tt, 0);
        STAGE_UNIT(B, col0, Bs, tt, tt, 1);
    }
    asm volatile("s_waitcnt vmcnt(8)" ::: "memory");   // tile 0 complete
    __builtin_amdgcn_s_barrier();

    for (int t = 0; t < nt; ++t) {
        const int buf = t & 3;
        const int tn  = (t + 3 < nt) ? (t + 3) : (nt - 1);
        const int nbuf = tn & 3;

        // ---- P0: A m0-3 + B n0-3; stage A(t+3) ----
#pragma unroll
        for (int m = 0; m < 4; ++m)
            fA[m] = *(const i32x4*)(&As[buf][rbA + m * 1024 + c0]);
#pragma unroll
        for (int n = 0; n < 4; ++n)
            fB[n] = *(const i32x4*)(&Bs[buf][rbB + n * 1024 + c0]);
        STAGE_UNIT(A, row0, As, nbuf, tn, 0);
        STAGE_UNIT(A, row0, As, nbuf, tn, 1);
        __builtin_amdgcn_sched_barrier(0);
        __builtin_amdgcn_s_barrier();
        asm volatile("s_waitcnt lgkmcnt(0)" ::: "memory");
        __builtin_amdgcn_sched_barrier(0);
        MFMA_Q(0);
        __builtin_amdgcn_s_barrier();

        // ---- P1: A m4-7; stage B(t+3); counted vmcnt ----
#pragma unroll
        for (int m = 0; m < 4; ++m)
            fA[m] = *(const i32x4*)(&As[buf][rbA + (m + 4) * 1024 + c0]);
        STAGE_UNIT(B, col0, Bs, nbuf, tn, 0);
        STAGE_UNIT(B, col0, Bs, nbuf, tn, 1);
        __builtin_amdgcn_sched_barrier(0);
        __builtin_amdgcn_s_barrier();
        asm volatile("s_waitcnt lgkmcnt(0)" ::: "memory");
        __builtin_amdgcn_sched_barrier(0);
        MFMA_Q(4);
        asm volatile("s_waitcnt vmcnt(8)" ::: "memory");
        __builtin_amdgcn_s_barrier();
    }
#undef STAGE_UNIT
#undef MFMA_Q

    // C/D frag mapping (gfx950, dtype-independent): col = lane&15, row = (lane>>4)*4 + reg
    if (EPI == 1) {
#pragma unroll
        for (int m = 0; m < 8; ++m) {
#pragma unroll
            for (int reg = 0; reg < 4; ++reg) {
                const int grow = row0 + (wm << 7) + m * 16 + l4 * 4 + reg;
                const float sa = scaleA[grow];
                float vmax = 0.0f;
#pragma unroll
                for (int n = 0; n < 4; ++n) {
                    const int gcol = col0 + (wn << 6) + n * 16 + l15;
                    const float y = (float)acc[m][n][reg] * sa * scaleB[gcol] + bias[gcol];
                    const float gl = 0.5f * y * (1.0f + erff(y * 0.70710678118654752f));
                    aout[(size_t)grow * DFF + gcol] = __float2bfloat16(gl);
                    vmax = fmaxf(vmax, fabsf(gl));
                }
#pragma unroll
                for (int off = 1; off < 16; off <<= 1)
                    vmax = fmaxf(vmax, __shfl_xor(vmax, off));
                if (l15 == 0) atomicMax(&rowmax[grow], __float_as_uint(vmax));
            }
        }
    } else {
#pragma unroll
        for (int m = 0; m < 8; ++m) {
#pragma unroll
            for (int reg = 0; reg < 4; ++reg) {
                const int grow = row0 + (wm << 7) + m * 16 + l4 * 4 + reg;
                const float s2 = fmaxf(__uint_as_float(rowmax[grow]) * (1.0f / 127.0f), 1e-8f);
#pragma unroll
                for (int n = 0; n < 4; ++n) {
                    const int gcol = col0 + (wn << 6) + n * 16 + l15;
                    out[(size_t)grow * Nout + gcol] =
                        (float)acc[m][n][reg] * s2 * scaleB[gcol] + bias[gcol];
                }
            }
        }
    }
}

// ---------------- dynamic requant: q2 = clip(rint(a / s2), -128, 127) ----------------
__global__ void quant_kernel(const unsigned short* __restrict__ a,  // bf16 bits
                             const unsigned* __restrict__ rowmax,
                             int8_t* __restrict__ q2)
{
    const size_t nvec = (size_t)TOKENS * DFF / 8;
    size_t i = (size_t)blockIdx.x * blockDim.x + threadIdx.x;
    const size_t stride = (size_t)gridDim.x * blockDim.x;
    for (; i < nvec; i += stride) {
        const size_t e0 = i * 8;
        const int n = (int)(e0 >> 14);  // / DFF
        const float s2 = fmaxf(__uint_as_float(rowmax[n]) * (1.0f / 127.0f), 1e-8f);
        const float inv = 1.0f / s2;
        const uint4 v = *(const uint4*)(a + e0);
        const unsigned words[4] = {v.x, v.y, v.z, v.w};
        int qi[8];
#pragma unroll
        for (int j = 0; j < 4; ++j) {
            const float f0 = __uint_as_float((words[j] & 0xffffu) << 16);
            const float f1 = __uint_as_float(words[j] & 0xffff0000u);
            qi[2 * j]     = (int)fminf(fmaxf(rintf(f0 * inv), -128.0f), 127.0f);
            qi[2 * j + 1] = (int)fminf(fmaxf(rintf(f1 * inv), -128.0f), 127.0f);
        }
        const unsigned p0 = (unsigned(qi[0]) & 255u) | ((unsigned(qi[1]) & 255u) << 8) |
                            ((unsigned(qi[2]) & 255u) << 16) | ((unsigned(qi[3]) & 255u) << 24);
        const unsigned p1 = (unsigned(qi[4]) & 255u) | ((unsigned(qi[5]) & 255u) << 8) |
                            ((unsigned(qi[6]) & 255u) << 16) | ((unsigned(qi[7]) & 255u) << 24);
        ((uint2*)q2)[i] = make_uint2(p0, p1);
    }
}

extern "C" void kernel_launch(void* const* d_in, const int* in_sizes, int n_in,
                              void* d_out, int out_size, void* d_ws, size_t ws_size,
                              hipStream_t stream) {
    const int*   q_in     = (const int*)d_in[0];
    const float* in_scale = (const float*)d_in[1];
    const int*   w1_q     = (const int*)d_in[2];
    const float* w1_scale = (const float*)d_in[3];
    const float* b1       = (const float*)d_in[4];
    const int*   w2_q     = (const int*)d_in[5];
    const float* w2_scale = (const float*)d_in[6];
    const float* b2       = (const float*)d_in[7];
    float* out = (float*)d_out;

    // workspace layout (total 336 MiB + 16 KiB)
    char* ws = (char*)d_ws;
    int8_t* A1 = (int8_t*)(ws);                                  //  16 MiB  q_in int8
    int8_t* W1 = (int8_t*)(ws + (size_t)16  * 1048576);          //  64 MiB
    int8_t* W2 = (int8_t*)(ws + (size_t)80  * 1048576);          //  64 MiB
    int8_t* Q2 = (int8_t*)(ws + (size_t)144 * 1048576);          //  64 MiB
    unsigned short* ABUF = (unsigned short*)(ws + (size_t)208 * 1048576);  // 128 MiB bf16 acts
    unsigned* ROWMAX = (unsigned*)(ws + (size_t)336 * 1048576);  //  16 KiB

    zero_u32_kernel<<<dim3(16), dim3(256), 0, stream>>>(ROWMAX, TOKENS);
    pack_i8_kernel<<<dim3(1024), dim3(256), 0, stream>>>(q_in, (unsigned*)A1, (long)TOKENS * DMODEL / 4);
    pack_i8_kernel<<<dim3(4096), dim3(256), 0, stream>>>(w1_q, (unsigned*)W1, (long)DFF * DMODEL / 4);
    pack_i8_kernel<<<dim3(4096), dim3(256), 0, stream>>>(w2_q, (unsigned*)W2, (long)DMODEL * DFF / 4);

    gemm_i8_kernel<1><<<dim3(DFF / 256, TOKENS / 256), dim3(512), 0, stream>>>(
        A1, W1, DFF, DMODEL, in_scale, w1_scale, b1, ROWMAX,
        (__hip_bfloat16*)ABUF, nullptr);

    quant_kernel<<<dim3(4096), dim3(256), 0, stream>>>(ABUF, ROWMAX, Q2);

    gemm_i8_kernel<2><<<dim3(DMODEL / 256, TOKENS / 256), dim3(512), 0, stream>>>(
        Q2, W2, DMODEL, DFF, nullptr, w2_scale, b2, ROWMAX,
        nullptr, out);
}

// Round 6
// 904.239 us; speedup vs baseline: 1.0822x; 1.0822x over previous
//
#include <hip/hip_runtime.h>
#include <hip/hip_bf16.h>
#include <cstdint>
#include <math.h>

#define TOKENS 4096
#define DMODEL 4096
#define DFF    16384

typedef __attribute__((ext_vector_type(4))) int i32x4;
typedef __attribute__((address_space(1))) unsigned int glb_u32;
typedef __attribute__((address_space(3))) unsigned int lds_u32;

// ---------------- pack: int32 -> int8 (values already in [-127,127]) ----------------
__global__ void pack_i8_kernel(const int* __restrict__ src, unsigned* __restrict__ dst, long n4) {
    long i = (long)blockIdx.x * blockDim.x + threadIdx.x;
    const long stride = (long)gridDim.x * blockDim.x;
    for (; i < n4; i += stride) {
        const int4 v = ((const int4*)src)[i];
        unsigned p = (unsigned(v.x) & 255u) | ((unsigned(v.y) & 255u) << 8) |
                     ((unsigned(v.z) & 255u) << 16) | ((unsigned(v.w) & 255u) << 24);
        dst[i] = p;
    }
}

__global__ void zero_u32_kernel(unsigned* __restrict__ p, int n) {
    int i = blockIdx.x * blockDim.x + threadIdx.x;
    if (i < n) p[i] = 0u;
}

// ---------------- int8 GEMM, C[row][col] = sum_k A[row][k]*B[col][k] ----------------
// 256x256 tile, BK=64, 16 waves (4M x 4N), wave tile 64x64 via 4x4 frags of
// 16x16x64 i8 MFMA (acc 4x4 = 64 regs). 4 waves/SIMD for latency hiding
// (R1-R5 showed 2 waves/SIMD lockstep pins at ~23% MfmaUtil regardless of
// schedule). Tri-buffered LDS (3 x 32KB), stage-ahead-2, ONE barrier/K-tile:
//   per tile t: stage(t+2 -> (t+2)%3); ds_read 8 frags (buf t%3);
//               [compiler fine-grained lgkm waits] 16 MFMA;
//               vmcnt(2) (completes t+1, leaves t+2 in flight); s_barrier
// Race audit: buf (t+2)%3 was last read at tile t-1; those reads completed
// (own-wave lgkm) before each wave's MFMA, which precede tile t-1's end
// barrier -> stage issued at tile t cannot overwrite live reads. Cross-wave
// staged-data visibility: each wave's vmcnt(2) completes ITS tile-t+1 loads;
// the following barrier makes them visible to all. No timing assumptions.
// LDS swizzle (R5-proven, 0 conflicts): 64B rows, chunk ^= (row>>1)&3;
// staging dest linear, source pre-swizzled g16 (lane-constant).
// XCD 2D chunking (R5-proven: FETCH 542->197MB): 8 XCDs as 2x4 over tiles.
template <int EPI>
__global__ __launch_bounds__(1024)
void gemm_i8_kernel(const int8_t* __restrict__ A,
                    const int8_t* __restrict__ B,
                    const int Nout, const int K,
                    const float* __restrict__ scaleA,   // EPI1: in_scale[row]
                    const float* __restrict__ scaleB,   // w1_scale / w2_scale [col]
                    const float* __restrict__ bias,     // b1 / b2 [col]
                    unsigned* __restrict__ rowmax,      // EPI1: atomic out; EPI2: in
                    __hip_bfloat16* __restrict__ aout,  // EPI1: activations out
                    float* __restrict__ out)            // EPI2: final out
{
    __shared__ int8_t As[3][256 * 64];
    __shared__ int8_t Bs[3][256 * 64];

    const int tid  = threadIdx.x;
    const int lane = tid & 63;
    const int w    = tid >> 6;          // 0..15
    const int wm   = w >> 2;            // 0..3  (M quarter: 64 rows)
    const int wn   = w & 3;             // 0..3  (N quarter: 64 cols)
    const int l15  = lane & 15, l4 = lane >> 4;

    // ---- XCD-aware 2D chunk mapping (bijective; gy%2==0, gx%4==0 here) ----
    const int gx = gridDim.x, gy = gridDim.y;
    const int wg  = blockIdx.y * gx + blockIdx.x;
    const int xcd = wg & 7;
    const int idx = wg >> 3;
    const int xr = xcd >> 2, xc = xcd & 3;          // XCDs as 2 x 4
    const int strip = idx >> 5;
    const int row_t = xr * (gy >> 1) + ((idx & 31) >> 2);
    const int col_t = xc * (gx >> 2) + strip * 4 + (idx & 3);
    const int row0 = row_t * 256;
    const int col0 = col_t * 256;

    const int nt = K >> 6;

    // staging: pre-swizzled lane-constant source chunk for 64B rows
    const int g16 = ((lane & 3) ^ ((lane >> 3) & 3)) << 4;

    // frag ds_read addressing: row r, chunk c = l4 ^ ((r>>1)&3); (r>>1)&3 == (l15>>1)&3
    const int rbA = ((wm << 6) + l15) << 6;          // byte base; + m*1024
    const int rbB = ((wn << 6) + l15) << 6;          // byte base; + n*1024
    const int c0  = (l4 ^ ((l15 >> 1) & 3)) << 4;

    i32x4 acc[4][4] = {};

    // per K-tile: wave w stages A rows [w*16,w*16+16) and same for B (1KB each)
#define STAGE(t, bufi)                                                                \
    {                                                                                 \
        const int8_t* sa_ = A + (size_t)(row0 + (w << 4) + (lane >> 2)) * K +         \
                            ((t) << 6) + g16;                                         \
        const int8_t* sb_ = B + (size_t)(col0 + (w << 4) + (lane >> 2)) * K +         \
                            ((t) << 6) + g16;                                         \
        __builtin_amdgcn_global_load_lds((glb_u32*)sa_, (lds_u32*)&As[bufi][w << 10], \
                                         16, 0, 0);                                   \
        __builtin_amdgcn_global_load_lds((glb_u32*)sb_, (lds_u32*)&Bs[bufi][w << 10], \
                                         16, 0, 0);                                   \
    }

    // prologue: stage tiles 0,1 into bufs 0,1
    STAGE(0, 0);
    STAGE(1, 1);
    asm volatile("s_waitcnt vmcnt(2)" ::: "memory");   // tile 0 complete
    __builtin_amdgcn_s_barrier();

    int buf = 0, sbuf = 2;
    for (int t = 0; t < nt; ++t) {
        if (t < nt - 2) STAGE(t + 2, sbuf);

        i32x4 fA[4], fB[4];
#pragma unroll
        for (int m = 0; m < 4; ++m)
            fA[m] = *(const i32x4*)(&As[buf][rbA + m * 1024 + c0]);
#pragma unroll
        for (int n = 0; n < 4; ++n)
            fB[n] = *(const i32x4*)(&Bs[buf][rbB + n * 1024 + c0]);

        __builtin_amdgcn_s_setprio(1);
#pragma unroll
        for (int m = 0; m < 4; ++m)
#pragma unroll
            for (int n = 0; n < 4; ++n)
                acc[m][n] = __builtin_amdgcn_mfma_i32_16x16x64_i8(fA[m], fB[n], acc[m][n], 0, 0, 0);
        __builtin_amdgcn_s_setprio(0);

        if (t < nt - 2) {
            asm volatile("s_waitcnt vmcnt(2)" ::: "memory");  // tile t+1 complete
        } else {
            asm volatile("s_waitcnt vmcnt(0)" ::: "memory");  // tail drain
        }
        __builtin_amdgcn_s_barrier();

        buf  = (buf  == 2) ? 0 : buf + 1;
        sbuf = (sbuf == 2) ? 0 : sbuf + 1;
    }
#undef STAGE

    // C/D frag mapping (gfx950, dtype-independent): col = lane&15, row = (lane>>4)*4 + reg
    if (EPI == 1) {
#pragma unroll
        for (int m = 0; m < 4; ++m) {
#pragma unroll
            for (int reg = 0; reg < 4; ++reg) {
                const int grow = row0 + (wm << 6) + m * 16 + l4 * 4 + reg;
                const float sa = scaleA[grow];
                float vmax = 0.0f;
#pragma unroll
                for (int n = 0; n < 4; ++n) {
                    const int gcol = col0 + (wn << 6) + n * 16 + l15;
                    const float y = (float)acc[m][n][reg] * sa * scaleB[gcol] + bias[gcol];
                    const float gl = 0.5f * y * (1.0f + erff(y * 0.70710678118654752f));
                    aout[(size_t)grow * DFF + gcol] = __float2bfloat16(gl);
                    vmax = fmaxf(vmax, fabsf(gl));
                }
#pragma unroll
                for (int off = 1; off < 16; off <<= 1)
                    vmax = fmaxf(vmax, __shfl_xor(vmax, off));
                if (l15 == 0) atomicMax(&rowmax[grow], __float_as_uint(vmax));
            }
        }
    } else {
#pragma unroll
        for (int m = 0; m < 4; ++m) {
#pragma unroll
            for (int reg = 0; reg < 4; ++reg) {
                const int grow = row0 + (wm << 6) + m * 16 + l4 * 4 + reg;
                const float s2 = fmaxf(__uint_as_float(rowmax[grow]) * (1.0f / 127.0f), 1e-8f);
#pragma unroll
                for (int n = 0; n < 4; ++n) {
                    const int gcol = col0 + (wn << 6) + n * 16 + l15;
                    out[(size_t)grow * Nout + gcol] =
                        (float)acc[m][n][reg] * s2 * scaleB[gcol] + bias[gcol];
                }
            }
        }
    }
}

// ---------------- dynamic requant: q2 = clip(rint(a / s2), -128, 127) ----------------
__global__ void quant_kernel(const unsigned short* __restrict__ a,  // bf16 bits
                             const unsigned* __restrict__ rowmax,
                             int8_t* __restrict__ q2)
{
    const size_t nvec = (size_t)TOKENS * DFF / 8;
    size_t i = (size_t)blockIdx.x * blockDim.x + threadIdx.x;
    const size_t stride = (size_t)gridDim.x * blockDim.x;
    for (; i < nvec; i += stride) {
        const size_t e0 = i * 8;
        const int n = (int)(e0 >> 14);  // / DFF
        const float s2 = fmaxf(__uint_as_float(rowmax[n]) * (1.0f / 127.0f), 1e-8f);
        const float inv = 1.0f / s2;
        const uint4 v = *(const uint4*)(a + e0);
        const unsigned words[4] = {v.x, v.y, v.z, v.w};
        int qi[8];
#pragma unroll
        for (int j = 0; j < 4; ++j) {
            const float f0 = __uint_as_float((words[j] & 0xffffu) << 16);
            const float f1 = __uint_as_float(words[j] & 0xffff0000u);
            qi[2 * j]     = (int)fminf(fmaxf(rintf(f0 * inv), -128.0f), 127.0f);
            qi[2 * j + 1] = (int)fminf(fmaxf(rintf(f1 * inv), -128.0f), 127.0f);
        }
        const unsigned p0 = (unsigned(qi[0]) & 255u) | ((unsigned(qi[1]) & 255u) << 8) |
                            ((unsigned(qi[2]) & 255u) << 16) | ((unsigned(qi[3]) & 255u) << 24);
        const unsigned p1 = (unsigned(qi[4]) & 255u) | ((unsigned(qi[5]) & 255u) << 8) |
                            ((unsigned(qi[6]) & 255u) << 16) | ((unsigned(qi[7]) & 255u) << 24);
        ((uint2*)q2)[i] = make_uint2(p0, p1);
    }
}

extern "C" void kernel_launch(void* const* d_in, const int* in_sizes, int n_in,
                              void* d_out, int out_size, void* d_ws, size_t ws_size,
                              hipStream_t stream) {
    const int*   q_in     = (const int*)d_in[0];
    const float* in_scale = (const float*)d_in[1];
    const int*   w1_q     = (const int*)d_in[2];
    const float* w1_scale = (const float*)d_in[3];
    const float* b1       = (const float*)d_in[4];
    const int*   w2_q     = (const int*)d_in[5];
    const float* w2_scale = (const float*)d_in[6];
    const float* b2       = (const float*)d_in[7];
    float* out = (float*)d_out;

    // workspace layout (total 336 MiB + 16 KiB)
    char* ws = (char*)d_ws;
    int8_t* A1 = (int8_t*)(ws);                                  //  16 MiB  q_in int8
    int8_t* W1 = (int8_t*)(ws + (size_t)16  * 1048576);          //  64 MiB
    int8_t* W2 = (int8_t*)(ws + (size_t)80  * 1048576);          //  64 MiB
    int8_t* Q2 = (int8_t*)(ws + (size_t)144 * 1048576);          //  64 MiB
    unsigned short* ABUF = (unsigned short*)(ws + (size_t)208 * 1048576);  // 128 MiB bf16 acts
    unsigned* ROWMAX = (unsigned*)(ws + (size_t)336 * 1048576);  //  16 KiB

    zero_u32_kernel<<<dim3(16), dim3(256), 0, stream>>>(ROWMAX, TOKENS);
    pack_i8_kernel<<<dim3(1024), dim3(256), 0, stream>>>(q_in, (unsigned*)A1, (long)TOKENS * DMODEL / 4);
    pack_i8_kernel<<<dim3(4096), dim3(256), 0, stream>>>(w1_q, (unsigned*)W1, (long)DFF * DMODEL / 4);
    pack_i8_kernel<<<dim3(4096), dim3(256), 0, stream>>>(w2_q, (unsigned*)W2, (long)DMODEL * DFF / 4);

    gemm_i8_kernel<1><<<dim3(DFF / 256, TOKENS / 256), dim3(1024), 0, stream>>>(
        A1, W1, DFF, DMODEL, in_scale, w1_scale, b1, ROWMAX,
        (__hip_bfloat16*)ABUF, nullptr);

    quant_kernel<<<dim3(4096), dim3(256), 0, stream>>>(ABUF, ROWMAX, Q2);

    gemm_i8_kernel<2><<<dim3(DMODEL / 256, TOKENS / 256), dim3(1024), 0, stream>>>(
        Q2, W2, DMODEL, DFF, nullptr, w2_scale, b2, ROWMAX,
        nullptr, out);
}

// Round 7
// 825.642 us; speedup vs baseline: 1.1853x; 1.0952x over previous
//
#include <hip/hip_runtime.h>
#include <hip/hip_bf16.h>
#include <cstdint>
#include <math.h>

#define TOKENS 4096
#define DMODEL 4096
#define DFF    16384

typedef __attribute__((ext_vector_type(4))) int i32x4;
typedef __attribute__((address_space(1))) unsigned int glb_u32;
typedef __attribute__((address_space(3))) unsigned int lds_u32;

// ---------------- pack: int32 -> int8 (values already in [-127,127]) ----------------
__global__ void pack_i8_kernel(const int* __restrict__ src, unsigned* __restrict__ dst, long n4) {
    long i = (long)blockIdx.x * blockDim.x + threadIdx.x;
    const long stride = (long)gridDim.x * blockDim.x;
    for (; i < n4; i += stride) {
        const int4 v = ((const int4*)src)[i];
        unsigned p = (unsigned(v.x) & 255u) | ((unsigned(v.y) & 255u) << 8) |
                     ((unsigned(v.z) & 255u) << 16) | ((unsigned(v.w) & 255u) << 24);
        dst[i] = p;
    }
}

__global__ void zero_u32_kernel(unsigned* __restrict__ p, int n) {
    int i = blockIdx.x * blockDim.x + threadIdx.x;
    if (i < n) p[i] = 0u;
}

// ---------------- int8 GEMM, C[row][col] = sum_k A[row][k]*B[col][k] ----------------
// 128x256 tile, BK=64, 512 threads (8 waves, 2M x 4N), wave tile 64x64 via 4x4
// frags of 16x16x64 i8 MFMA. LDS = 3 bufs x (8KB A + 16KB B) = 72KB ->
// TWO co-resident blocks per CU (R6 lesson: one 16-wave barrier domain locksteps
// the whole CU; two independent 8-wave domains fill each other's stalls).
// Same loop as R6: stage(t+2); ds_read 8 frags (compiler fine-grained lgkm);
// 16 MFMA; vmcnt(3) (completes t+1, leaves t+2 in flight); s_barrier.
// Race audit: identical to R6 (3 bufs, stage target == buf read at t-1 whose
// reads complete before t-1's end barrier; own-wave vmcnt(3) + barrier makes
// t+1 staged data visible). Staging: 3 gloads/thread (A slot tid, B slots
// tid, tid+512); swizzle term ((s>>3)&3) invariant under +512 -> one g16.
// LDS swizzle (proven, 0 conflicts): 64B rows, chunk ^= (row>>1)&3.
// XCD 2D chunking: 8 XCDs as 2x4; within each XCD's 16x(gx/4) tile region,
// column-major idx -> 64 resident blocks form a 16x4 patch.
template <int EPI>
__global__ __launch_bounds__(512)
void gemm_i8_kernel(const int8_t* __restrict__ A,
                    const int8_t* __restrict__ B,
                    const int Nout, const int K,
                    const float* __restrict__ scaleA,   // EPI1: in_scale[row]
                    const float* __restrict__ scaleB,   // w1_scale / w2_scale [col]
                    const float* __restrict__ bias,     // b1 / b2 [col]
                    unsigned* __restrict__ rowmax,      // EPI1: atomic out; EPI2: in
                    __hip_bfloat16* __restrict__ aout,  // EPI1: activations out
                    float* __restrict__ out)            // EPI2: final out
{
    __shared__ int8_t As[3][128 * 64];
    __shared__ int8_t Bs[3][256 * 64];

    const int tid  = threadIdx.x;
    const int lane = tid & 63;
    const int w    = tid >> 6;          // 0..7
    const int wm   = w >> 2;            // 0..1  (M half: 64 rows each)
    const int wn   = w & 3;             // 0..3  (N quarter: 64 cols)
    const int l15  = lane & 15, l4 = lane >> 4;

    // ---- XCD-aware 2D chunk mapping (bijective; gy==32, gx%4==0 here) ----
    const int gx = gridDim.x;
    const int wg  = blockIdx.y * gx + blockIdx.x;
    const int xcd = wg & 7;
    const int idx = wg >> 3;
    const int xr = xcd >> 2, xc = xcd & 3;          // XCDs as 2 x 4
    const int row_t = xr * 16 + (idx & 15);          // column-major in region
    const int col_t = xc * (gx >> 2) + (idx >> 4);
    const int row0 = row_t * 128;
    const int col0 = col_t * 256;

    const int nt = K >> 6;

    // staging: slot s -> row s>>2, chunk (s&3)^((s>>3)&3); one g16 for all slots
    const int srow = tid >> 2;
    const int g16  = ((tid & 3) ^ ((tid >> 3) & 3)) << 4;

    // frag ds_read addressing: row r, chunk c = l4 ^ ((r>>1)&3); (r>>1)&3 == (l15>>1)&3
    const int rbA = ((wm << 6) + l15) << 6;          // byte base; + m*1024
    const int rbB = ((wn << 6) + l15) << 6;          // byte base; + n*1024
    const int c0  = (l4 ^ ((l15 >> 1) & 3)) << 4;

    i32x4 acc[4][4] = {};

    // per K-tile: A 8KB (1 load/thread), B 16KB (2 loads/thread)
#define STAGE(t, bufi)                                                                \
    {                                                                                 \
        const int k0_ = (t) << 6;                                                     \
        const int8_t* sa_ = A + (size_t)(row0 + srow) * K + k0_ + g16;                \
        const int8_t* sb0 = B + (size_t)(col0 + srow) * K + k0_ + g16;                \
        const int8_t* sb1 = B + (size_t)(col0 + 128 + srow) * K + k0_ + g16;          \
        __builtin_amdgcn_global_load_lds((glb_u32*)sa_,                               \
            (lds_u32*)&As[bufi][tid << 4], 16, 0, 0);                                 \
        __builtin_amdgcn_global_load_lds((glb_u32*)sb0,                               \
            (lds_u32*)&Bs[bufi][tid << 4], 16, 0, 0);                                 \
        __builtin_amdgcn_global_load_lds((glb_u32*)sb1,                               \
            (lds_u32*)&Bs[bufi][(tid + 512) << 4], 16, 0, 0);                         \
    }

    // prologue: stage tiles 0,1 into bufs 0,1
    STAGE(0, 0);
    STAGE(1, 1);
    asm volatile("s_waitcnt vmcnt(3)" ::: "memory");   // tile 0 complete
    __builtin_amdgcn_s_barrier();

    int buf = 0, sbuf = 2;
    for (int t = 0; t < nt; ++t) {
        if (t < nt - 2) STAGE(t + 2, sbuf);

        i32x4 fA[4], fB[4];
#pragma unroll
        for (int m = 0; m < 4; ++m)
            fA[m] = *(const i32x4*)(&As[buf][rbA + m * 1024 + c0]);
#pragma unroll
        for (int n = 0; n < 4; ++n)
            fB[n] = *(const i32x4*)(&Bs[buf][rbB + n * 1024 + c0]);

        __builtin_amdgcn_s_setprio(1);
#pragma unroll
        for (int m = 0; m < 4; ++m)
#pragma unroll
            for (int n = 0; n < 4; ++n)
                acc[m][n] = __builtin_amdgcn_mfma_i32_16x16x64_i8(fA[m], fB[n], acc[m][n], 0, 0, 0);
        __builtin_amdgcn_s_setprio(0);

        if (t < nt - 2) {
            asm volatile("s_waitcnt vmcnt(3)" ::: "memory");  // tile t+1 complete
        } else {
            asm volatile("s_waitcnt vmcnt(0)" ::: "memory");  // tail drain
        }
        __builtin_amdgcn_s_barrier();

        buf  = (buf  == 2) ? 0 : buf + 1;
        sbuf = (sbuf == 2) ? 0 : sbuf + 1;
    }
#undef STAGE

    // C/D frag mapping (gfx950, dtype-independent): col = lane&15, row = (lane>>4)*4 + reg
    if (EPI == 1) {
#pragma unroll
        for (int m = 0; m < 4; ++m) {
#pragma unroll
            for (int reg = 0; reg < 4; ++reg) {
                const int grow = row0 + (wm << 6) + m * 16 + l4 * 4 + reg;
                const float sa = scaleA[grow];
                float vmax = 0.0f;
#pragma unroll
                for (int n = 0; n < 4; ++n) {
                    const int gcol = col0 + (wn << 6) + n * 16 + l15;
                    const float y = (float)acc[m][n][reg] * sa * scaleB[gcol] + bias[gcol];
                    const float gl = 0.5f * y * (1.0f + erff(y * 0.70710678118654752f));
                    aout[(size_t)grow * DFF + gcol] = __float2bfloat16(gl);
                    vmax = fmaxf(vmax, fabsf(gl));
                }
#pragma unroll
                for (int off = 1; off < 16; off <<= 1)
                    vmax = fmaxf(vmax, __shfl_xor(vmax, off));
                if (l15 == 0) atomicMax(&rowmax[grow], __float_as_uint(vmax));
            }
        }
    } else {
#pragma unroll
        for (int m = 0; m < 4; ++m) {
#pragma unroll
            for (int reg = 0; reg < 4; ++reg) {
                const int grow = row0 + (wm << 6) + m * 16 + l4 * 4 + reg;
                const float s2 = fmaxf(__uint_as_float(rowmax[grow]) * (1.0f / 127.0f), 1e-8f);
#pragma unroll
                for (int n = 0; n < 4; ++n) {
                    const int gcol = col0 + (wn << 6) + n * 16 + l15;
                    out[(size_t)grow * Nout + gcol] =
                        (float)acc[m][n][reg] * s2 * scaleB[gcol] + bias[gcol];
                }
            }
        }
    }
}

// ---------------- dynamic requant: q2 = clip(rint(a / s2), -128, 127) ----------------
__global__ void quant_kernel(const unsigned short* __restrict__ a,  // bf16 bits
                             const unsigned* __restrict__ rowmax,
                             int8_t* __restrict__ q2)
{
    const size_t nvec = (size_t)TOKENS * DFF / 8;
    size_t i = (size_t)blockIdx.x * blockDim.x + threadIdx.x;
    const size_t stride = (size_t)gridDim.x * blockDim.x;
    for (; i < nvec; i += stride) {
        const size_t e0 = i * 8;
        const int n = (int)(e0 >> 14);  // / DFF
        const float s2 = fmaxf(__uint_as_float(rowmax[n]) * (1.0f / 127.0f), 1e-8f);
        const float inv = 1.0f / s2;
        const uint4 v = *(const uint4*)(a + e0);
        const unsigned words[4] = {v.x, v.y, v.z, v.w};
        int qi[8];
#pragma unroll
        for (int j = 0; j < 4; ++j) {
            const float f0 = __uint_as_float((words[j] & 0xffffu) << 16);
            const float f1 = __uint_as_float(words[j] & 0xffff0000u);
            qi[2 * j]     = (int)fminf(fmaxf(rintf(f0 * inv), -128.0f), 127.0f);
            qi[2 * j + 1] = (int)fminf(fmaxf(rintf(f1 * inv), -128.0f), 127.0f);
        }
        const unsigned p0 = (unsigned(qi[0]) & 255u) | ((unsigned(qi[1]) & 255u) << 8) |
                            ((unsigned(qi[2]) & 255u) << 16) | ((unsigned(qi[3]) & 255u) << 24);
        const unsigned p1 = (unsigned(qi[4]) & 255u) | ((unsigned(qi[5]) & 255u) << 8) |
                            ((unsigned(qi[6]) & 255u) << 16) | ((unsigned(qi[7]) & 255u) << 24);
        ((uint2*)q2)[i] = make_uint2(p0, p1);
    }
}

extern "C" void kernel_launch(void* const* d_in, const int* in_sizes, int n_in,
                              void* d_out, int out_size, void* d_ws, size_t ws_size,
                              hipStream_t stream) {
    const int*   q_in     = (const int*)d_in[0];
    const float* in_scale = (const float*)d_in[1];
    const int*   w1_q     = (const int*)d_in[2];
    const float* w1_scale = (const float*)d_in[3];
    const float* b1       = (const float*)d_in[4];
    const int*   w2_q     = (const int*)d_in[5];
    const float* w2_scale = (const float*)d_in[6];
    const float* b2       = (const float*)d_in[7];
    float* out = (float*)d_out;

    // workspace layout (total 336 MiB + 16 KiB)
    char* ws = (char*)d_ws;
    int8_t* A1 = (int8_t*)(ws);                                  //  16 MiB  q_in int8
    int8_t* W1 = (int8_t*)(ws + (size_t)16  * 1048576);          //  64 MiB
    int8_t* W2 = (int8_t*)(ws + (size_t)80  * 1048576);          //  64 MiB
    int8_t* Q2 = (int8_t*)(ws + (size_t)144 * 1048576);          //  64 MiB
    unsigned short* ABUF = (unsigned short*)(ws + (size_t)208 * 1048576);  // 128 MiB bf16 acts
    unsigned* ROWMAX = (unsigned*)(ws + (size_t)336 * 1048576);  //  16 KiB

    zero_u32_kernel<<<dim3(16), dim3(256), 0, stream>>>(ROWMAX, TOKENS);
    pack_i8_kernel<<<dim3(1024), dim3(256), 0, stream>>>(q_in, (unsigned*)A1, (long)TOKENS * DMODEL / 4);
    pack_i8_kernel<<<dim3(4096), dim3(256), 0, stream>>>(w1_q, (unsigned*)W1, (long)DFF * DMODEL / 4);
    pack_i8_kernel<<<dim3(4096), dim3(256), 0, stream>>>(w2_q, (unsigned*)W2, (long)DMODEL * DFF / 4);

    gemm_i8_kernel<1><<<dim3(DFF / 256, TOKENS / 128), dim3(512), 0, stream>>>(
        A1, W1, DFF, DMODEL, in_scale, w1_scale, b1, ROWMAX,
        (__hip_bfloat16*)ABUF, nullptr);

    quant_kernel<<<dim3(4096), dim3(256), 0, stream>>>(ABUF, ROWMAX, Q2);

    gemm_i8_kernel<2><<<dim3(DMODEL / 256, TOKENS / 128), dim3(512), 0, stream>>>(
        Q2, W2, DMODEL, DFF, nullptr, w2_scale, b2, ROWMAX,
        nullptr, out);
}